// Round 16
// baseline (4549.254 us; speedup 1.0000x reference)
//
#include <hip/hip_runtime.h>
#include <hip/hip_bf16.h>
#include <hip/hip_fp8.h>

// ---------------------------------------------------------------------------
// UnifiedModelRNN: B=256,S=512,I=64,H=256. 16 blocks x 1024 threads (16 waves,
// 4/SIMD); block g owns batch rows [16g,16g+16). No grid sync.
// R16 = R14's dataflow at 16 waves for TLP:
//  * Wave w owns hidden [16w,16w+16) x 4 gates: acc2[4]. fp8 gate path
//    (weights + A-operands) via mfma_f32_16x16x32_fp8_fp8; c-state f32.
//  * Gate stream: 40 frags/wave (20KB/step), chunk = one kt (4 frags, 2 DMA
//    ops). 2-slot ring/wave (16x2x2KB = 64KB), ONE chunk in flight:
//    consume c {vmcnt(2); 4 ds_read_b64 + 4 MFMA; lgkmcnt(0)} -> issue c+2.
//    offset=0 exact-pointer DMAs (imm-offset arg corrupts LDS dst, R10-13).
//  * Head roles: w0-3 pit1, w4-7 time1, w8-11 ar1, w12-15 ar2. pit/time
//    weights bf16 LDS-resident (R15 showed streaming them regresses);
//    ar weights register-resident. Heads run on bf16 h (A_lds).
//  * lgkm-only barriers; 5 barriers/step; same phase order as R14.
// ---------------------------------------------------------------------------

typedef float f32x4 __attribute__((ext_vector_type(4)));
typedef short s16x8 __attribute__((ext_vector_type(8)));

#define S_LEN 512
#define I_DIM 64
#define NT    1024

// ws byte offsets
#define WSTRIDE8 20480    // bytes per wave fp8 gate stream (40 frags x 512B)
#define WSB_BF   327680   // bf16 region (u16 elems): pit 16384, tim 16384,
                          //   arx 4096, ar2 4096
#define PREP_N   368640

#define OUT_PIT  0
#define OUT_TIME 131072
#define OUT_AR   262144

#define ALD 328   // bf16 [x|h] row stride (elems)
#define AF8 336   // fp8  [x|h] row stride (bytes)
#define XLD 72

__device__ __forceinline__ float sigf(float x) {
  return 1.0f / (1.0f + __expf(-x));
}
__device__ __forceinline__ float tanh_fast(float x) {
  float c = fminf(fmaxf(x, -15.0f), 15.0f);
  float e = __expf(2.0f * c);
  return (e - 1.0f) / (e + 1.0f);
}
__device__ __forceinline__ unsigned short f2bf(float f) {
  __hip_bfloat16 h = __float2bfloat16(f);
  return *reinterpret_cast<unsigned short*>(&h);
}
__device__ __forceinline__ unsigned char f2f8(float v) {
  __hip_fp8_e4m3 q(v);
  return *reinterpret_cast<unsigned char*>(&q);
}
// LDS-only barrier: does NOT drain vmcnt -> DMA stays in flight.
__device__ __forceinline__ void sync_lds() {
  asm volatile("s_waitcnt lgkmcnt(0)" ::: "memory");
  __builtin_amdgcn_s_barrier();
  asm volatile("" ::: "memory");
}
// 16B/lane global->LDS DMA, offset=0, exact pointers (proven form).
__device__ __forceinline__ void gld16(const void* g, void* l) {
  __builtin_amdgcn_global_load_lds(
      (const __attribute__((address_space(1))) unsigned int*)g,
      (__attribute__((address_space(3))) unsigned int*)l, 16, 0, 0);
}

__global__ void prep_kernel(const float* __restrict__ w_ih,
                            const float* __restrict__ w_hh,
                            const float* __restrict__ pit_w1,
                            const float* __restrict__ time_w1,
                            const float* __restrict__ ar_w1,
                            const float* __restrict__ ar_w2,
                            unsigned char* __restrict__ ws8) {
  int idx = blockIdx.x * 256 + threadIdx.x;
  if (idx >= PREP_N) return;
  if (idx < WSB_BF) {
    // fp8 gate byte: wave stream, consume order kt2..kt9,kt0,kt1 x q0..3
    int w  = idx / WSTRIDE8;
    int p8 = idx - w * WSTRIDE8;     // 0..20479
    int f  = p8 >> 9;                // frag 0..39
    int b  = p8 & 511;
    int lane = b >> 3, e = b & 7;
    int lrow = lane & 15, lgrp = lane >> 4;
    int ktidx = f >> 2, q = f & 3;
    int kt = (ktidx < 8) ? ktidx + 2 : ktidx - 8;   // kt2..kt9,kt0,kt1
    int row = q * 256 + w * 16 + lrow;
    int col = kt * 32 + lgrp * 8 + e;
    float v = (col < I_DIM) ? w_ih[row * I_DIM + col]
                            : w_hh[row * 256 + col - I_DIM];
    ws8[idx] = f2f8(v);
  } else {
    // bf16 element
    int e2 = idx - WSB_BF;           // 0..40959
    int lane = (e2 >> 3) & 63;
    int e    = e2 & 7;
    int lrow = lane & 15, lgrp = lane >> 4;
    float v;
    if (e2 < 16384) {                // pit_w1: frag f = wv*8+kt
      int f = e2 >> 9, wv = f >> 3, kt = f & 7;
      v = pit_w1[(wv * 16 + lrow) * 256 + kt * 32 + lgrp * 8 + e];
    } else if (e2 < 32768) {         // time_w1[:, :256]
      int f = (e2 - 16384) >> 9, wv = f >> 3, kt = f & 7;
      v = time_w1[(wv * 16 + lrow) * 257 + kt * 32 + lgrp * 8 + e];
    } else if (e2 < 36864) {         // ar_w1[:, 2:66]: frag f = wv*2+kt
      int f = (e2 - 32768) >> 9, wv = f >> 1, kt = f & 1;
      v = ar_w1[(wv * 16 + lrow) * 66 + 2 + kt * 32 + lgrp * 8 + e];
    } else {                         // ar_w2
      int f = (e2 - 36864) >> 9, wv = f >> 1, kt = f & 1;
      v = ar_w2[(wv * 16 + lrow) * 64 + kt * 32 + lgrp * 8 + e];
    }
    ((unsigned short*)(ws8 + WSB_BF))[e2] = f2bf(v);
  }
}

// fp8 A-frag from A_f8 (byte cols): 8 bytes/lane.
#define A8FRAG(kt) (*(const long*)&A_f8[lrow][(kt) * 32 + 8 * lgrp])

// DMA one kt chunk (4 frags = 2KB = 2 ops) into stg8[wave][slot].
// Chunk i (i=0..9 over kt2..kt9,kt0,kt1) lives at byte i*2048 of the stream.
#define DMAC(byteoff, slot)                                                    \
  do {                                                                         \
    const unsigned char* g_ = wg8l + (byteoff);                                \
    gld16(g_,        &stg8[wave][slot][0]);                                    \
    gld16(g_ + 1024, &stg8[wave][slot][1024]);                                 \
  } while (0)

// Consume gate chunk (4 frags q=0..3) with fp8 A-frag af into acc2[q].
// vmcnt(2): this chunk landed, next chunk's 2 ops still in flight.
#define GCHUNK(af, slot)                                                       \
  do {                                                                         \
    asm volatile("s_waitcnt vmcnt(2)" ::: "memory");                           \
    _Pragma("unroll")                                                          \
    for (int q_ = 0; q_ < 4; ++q_) {                                           \
      long b_ = *(const long*)&stg8[wave][slot][q_ * 512 + lane * 8];          \
      acc2[q_] = __builtin_amdgcn_mfma_f32_16x16x32_fp8_fp8(                   \
          (af), b_, acc2[q_], 0, 0, 0);                                        \
    }                                                                          \
    asm volatile("s_waitcnt lgkmcnt(0)" ::: "memory");                         \
  } while (0)

__global__ __launch_bounds__(NT, 1) void rnn_kernel(
    const float* __restrict__ x,
    const float* __restrict__ b_ih, const float* __restrict__ b_hh,
    const float* __restrict__ pit_b1, const float* __restrict__ pit_w2,
    const float* __restrict__ pit_b2,
    const float* __restrict__ time_w1, const float* __restrict__ time_b1,
    const float* __restrict__ time_w2, const float* __restrict__ time_b2,
    const float* __restrict__ ar_w1, const float* __restrict__ ar_b1,
    const float* __restrict__ ar_b2,
    const unsigned char* __restrict__ ws8,
    float* __restrict__ out)
{
  __shared__ __align__(16) unsigned short A_lds[16][ALD];    // bf16 [x|h]
  __shared__ __align__(16) unsigned char  A_f8[16][AF8];     // fp8  [x|h]
  __shared__ __align__(16) unsigned short xo_lds[16][XLD];   // x_orig[t] bf16
  __shared__ __align__(16) unsigned short ar1_lds[16][XLD];  // relu(ar1) bf16
  __shared__ __align__(16) unsigned short pit_lds[32 * 512]; // pit_w1 (32 KB)
  __shared__ __align__(16) unsigned short tim_lds[32 * 512]; // time_w1 (32 KB)
  __shared__ __align__(16) unsigned char  stg8[16][2][2048]; // fp8 ring (64 KB)
  __shared__ float pitp[4][16];
  __shared__ float timep[4][16];

  const int tid  = threadIdx.x;
  const int wave = tid >> 6;     // 0..15
  const int lane = tid & 63;
  const int lrow = lane & 15;
  const int lgrp = lane >> 4;
  const int b0   = blockIdx.x * 16;
  const int hcol = (wave & 3) * 16 + lrow;
  const unsigned char* wg8l = ws8 + wave * WSTRIDE8 + lane * 16;  // DMA base
  const unsigned char* wg8  = ws8 + wave * WSTRIDE8;              // frag reads
  const unsigned short* wsb = (const unsigned short*)(ws8 + WSB_BF);

  // ---- one-time LDS staging: pit/tim bf16 weights ----
  for (int c = tid; c < 2048; c += NT) {
    *(s16x8*)&pit_lds[c * 8] = *(const s16x8*)&wsb[c * 8];
    *(s16x8*)&tim_lds[c * 8] = *(const s16x8*)&wsb[16384 + c * 8];
  }
  for (int i = tid; i < 16 * ALD; i += NT) (&A_lds[0][0])[i] = 0;
  for (int i = tid; i < 16 * AF8; i += NT) (&A_f8[0][0])[i] = 0;

  // ---- role constants ----
  float gbias[4];
#pragma unroll
  for (int q = 0; q < 4; ++q)
    gbias[q] = b_ih[q * 256 + wave * 16 + lrow] + b_hh[q * 256 + wave * 16 + lrow];

  s16x8 arw[2];
  float pb1v = 0, pw2v = 0, tb1v = 0, tw2v = 0, twlv = 0;
  float ab1v = 0, arpv = 0, artv = 0, ab2v = 0;
  if (wave < 4) {
    pb1v = pit_b1[hcol]; pw2v = pit_w2[hcol];
  } else if (wave < 8) {
    tb1v = time_b1[hcol]; tw2v = time_w2[hcol];
    twlv = time_w1[hcol * 257 + 256];
  } else if (wave < 12) {
    arw[0] = *(const s16x8*)&wsb[32768 + ((wave & 3) * 2 + 0) * 512 + lane * 8];
    arw[1] = *(const s16x8*)&wsb[32768 + ((wave & 3) * 2 + 1) * 512 + lane * 8];
    ab1v = ar_b1[hcol]; arpv = ar_w1[hcol * 66]; artv = ar_w1[hcol * 66 + 1];
  } else {
    arw[0] = *(const s16x8*)&wsb[36864 + ((wave & 3) * 2 + 0) * 512 + lane * 8];
    arw[1] = *(const s16x8*)&wsb[36864 + ((wave & 3) * 2 + 1) * 512 + lane * 8];
    ab2v = ar_b2[hcol];
  }
  const float pb2 = pit_b2[0], tb2 = time_b2[0];

  // ---- stage x[:,0,:] (bf16 + fp8), write ar_out[:,0,:]; 1 elem/thread ----
  const int srow = tid >> 6;          // 0..15
  const int scol = tid & 63;          // 0..63
  const size_t xbase = (size_t)(b0 + srow) * S_LEN * I_DIM + scol;
  float xpre = x[xbase];
  __syncthreads();
  A_lds[srow][scol] = f2bf(xpre);
  A_f8[srow][scol]  = f2f8(xpre);
  out[OUT_AR + xbase] = xpre;

  float cst[4] = {0.0f, 0.0f, 0.0f, 0.0f};
  __syncthreads();

  // ---- prologue: gates(0) = bias + x0-part; kt0 frags 32..35, kt1 36..39 ----
  f32x4 acc2[4];
#pragma unroll
  for (int q = 0; q < 4; ++q) {
    f32x4 tv; tv[0] = tv[1] = tv[2] = tv[3] = gbias[q];
    acc2[q] = tv;
  }
  {
    long a0 = A8FRAG(0);
#pragma unroll
    for (int q = 0; q < 4; ++q) {
      long b = *(const long*)(wg8 + (32 + q) * 512 + lane * 8);
      acc2[q] = __builtin_amdgcn_mfma_f32_16x16x32_fp8_fp8(a0, b, acc2[q], 0, 0, 0);
    }
    long a1 = A8FRAG(1);
#pragma unroll
    for (int q = 0; q < 4; ++q) {
      long b = *(const long*)(wg8 + (36 + q) * 512 + lane * 8);
      acc2[q] = __builtin_amdgcn_mfma_f32_16x16x32_fp8_fp8(a1, b, acc2[q], 0, 0, 0);
    }
  }
  // drain prologue plain loads, prime ring: c0=kt2 -> slot0, c1=kt3 -> slot1
  asm volatile("s_waitcnt vmcnt(0)" ::: "memory");
  DMAC(0, 0);
  DMAC(2048, 1);

  // =========================== time loop ===========================
  for (int t = 0; t < S_LEN; ++t) {
    // ---- P0: xo stage, x prefetch, LSTM -> h (bf16 + fp8) ----
    xo_lds[srow][scol] = f2bf(xpre);
    if (t + 1 < S_LEN) xpre = x[xbase + (size_t)(t + 1) * I_DIM];

#pragma unroll
    for (int r = 0; r < 4; ++r) {
      float ig = sigf(acc2[0][r]);
      float fg = sigf(acc2[1][r]);
      float gg = tanh_fast(acc2[2][r]);
      float og = sigf(acc2[3][r]);
      float c  = fg * cst[r] + ig * gg;
      cst[r] = c;
      float hv = og * tanh_fast(c);
      int row = lgrp * 4 + r, col = 64 + wave * 16 + lrow;
      A_lds[row][col] = f2bf(hv);
      A_f8[row][col]  = f2f8(hv);
    }
#pragma unroll
    for (int q = 0; q < 4; ++q) {
      f32x4 tv; tv[0] = tv[1] = tv[2] = tv[3] = gbias[q];
      acc2[q] = tv;
    }
    sync_lds();  // barrier A: h + xo ready

    // ---- P1: heads main (w0-7), ar1-x (w8-11); pit reduce; gates kt2-5 ----
    long hfr8[8];
#pragma unroll
    for (int k = 0; k < 8; ++k)
      hfr8[k] = *(const long*)&A_f8[lrow][64 + k * 32 + 8 * lgrp];

    f32x4 hacc, aracc;
    if (wave < 8) {
      float hb = (wave < 4) ? pb1v : tb1v;
      hacc[0] = hacc[1] = hacc[2] = hacc[3] = hb;
      const unsigned short* hbp = (wave < 4) ? pit_lds : tim_lds;
#pragma unroll
      for (int kt = 0; kt < 8; ++kt) {
        s16x8 aH = *(const s16x8*)&A_lds[lrow][64 + kt * 32 + 8 * lgrp];
        s16x8 bH = *(const s16x8*)&hbp[((wave & 3) * 8 + kt) * 512 + lane * 8];
        hacc = __builtin_amdgcn_mfma_f32_16x16x32_bf16(aH, bH, hacc, 0, 0, 0);
      }
    } else if (wave < 12) {
      aracc[0] = aracc[1] = aracc[2] = aracc[3] = ab1v;
#pragma unroll
      for (int kt = 0; kt < 2; ++kt) {
        s16x8 aX = *(const s16x8*)&xo_lds[lrow][kt * 32 + 8 * lgrp];
        aracc = __builtin_amdgcn_mfma_f32_16x16x32_bf16(aX, arw[kt], aracc, 0, 0, 0);
      }
    }
    if (wave < 4) {  // pit partial reduce
      float v[4];
#pragma unroll
      for (int r = 0; r < 4; ++r) v[r] = fmaxf(hacc[r], 0.0f) * pw2v;
#pragma unroll
      for (int off = 1; off < 16; off <<= 1)
#pragma unroll
        for (int r = 0; r < 4; ++r) v[r] += __shfl_xor(v[r], off);
      if (lrow == 0) {
#pragma unroll
        for (int r = 0; r < 4; ++r) pitp[wave][lgrp * 4 + r] = v[r];
      }
    }
    GCHUNK(hfr8[0], 0); DMAC(4096, 0);    // c0 kt2 -> issue c2 (kt4)
    GCHUNK(hfr8[1], 1); DMAC(6144, 1);    // c1 kt3 -> c3 (kt5)
    GCHUNK(hfr8[2], 0); DMAC(8192, 0);    // c2 kt4 -> c4 (kt6)
    GCHUNK(hfr8[3], 1); DMAC(10240, 1);   // c3 kt5 -> c5 (kt7)
    sync_lds();  // barrier 1: pit partials ready

    // ---- P2: pv; time finish (w4-7); pit out (w0); gates kt6,7 ----
    float pv[4];
#pragma unroll
    for (int r = 0; r < 4; ++r) {
      int row = lgrp * 4 + r;
      pv[r] = pitp[0][row] + pitp[1][row] + pitp[2][row] + pitp[3][row] + pb2;
    }
    if (wave >= 4 && wave < 8) {
      float v[4];
#pragma unroll
      for (int r = 0; r < 4; ++r)
        v[r] = fmaxf(hacc[r] + pv[r] * twlv, 0.0f) * tw2v;
#pragma unroll
      for (int off = 1; off < 16; off <<= 1)
#pragma unroll
        for (int r = 0; r < 4; ++r) v[r] += __shfl_xor(v[r], off);
      if (lrow == 0) {
#pragma unroll
        for (int r = 0; r < 4; ++r) timep[wave & 3][lgrp * 4 + r] = v[r];
      }
    } else if (wave == 0 && lane < 16) {
      float pvs = pitp[0][lane] + pitp[1][lane] + pitp[2][lane] + pitp[3][lane] + pb2;
      out[OUT_PIT + (size_t)(b0 + lane) * S_LEN + t] = pvs;
    }
    GCHUNK(hfr8[4], 0); DMAC(12288, 0);   // c4 kt6 -> c6 (kt8)
    GCHUNK(hfr8[5], 1); DMAC(14336, 1);   // c5 kt7 -> c7 (kt9)
    sync_lds();  // barrier 2: time partials ready

    // ---- P3: tv; ar1 finish (w8-11); time out (w4); gates kt8,9 ----
    float tvv[4];
#pragma unroll
    for (int r = 0; r < 4; ++r) {
      int row = lgrp * 4 + r;
      tvv[r] = timep[0][row] + timep[1][row] + timep[2][row] + timep[3][row] + tb2;
    }
    if (wave >= 8 && wave < 12) {
#pragma unroll
      for (int r = 0; r < 4; ++r) {
        float a1 = aracc[r] + pv[r] * arpv + tvv[r] * artv;
        ar1_lds[lgrp * 4 + r][hcol] = f2bf(fmaxf(a1, 0.0f));
      }
    } else if (wave == 4 && lane < 16) {
      float tvs = timep[0][lane] + timep[1][lane] + timep[2][lane] + timep[3][lane] + tb2;
      out[OUT_TIME + (size_t)(b0 + lane) * S_LEN + t] = tvs;
    }
    GCHUNK(hfr8[6], 0); DMAC(16384, 0);   // c6 kt8 -> c8 (kt0)
    GCHUNK(hfr8[7], 1); DMAC(18432, 1);   // c7 kt9 -> c9 (kt1)
    sync_lds();  // barrier 3: ar1 ready

    // ---- P4: ar2 -> x_{t+1} (w12-15), bf16 + fp8 ----
    if (wave >= 12) {
      f32x4 nacc;
      nacc[0] = nacc[1] = nacc[2] = nacc[3] = ab2v;
#pragma unroll
      for (int kt = 0; kt < 2; ++kt) {
        s16x8 aR = *(const s16x8*)&ar1_lds[lrow][kt * 32 + 8 * lgrp];
        nacc = __builtin_amdgcn_mfma_f32_16x16x32_bf16(aR, arw[kt], nacc, 0, 0, 0);
      }
#pragma unroll
      for (int r = 0; r < 4; ++r) {
        int row = lgrp * 4 + r;
        float nv = nacc[r];
        A_lds[row][hcol] = f2bf(nv);
        A_f8[row][hcol]  = f2f8(nv);
        if (t < S_LEN - 1)
          out[OUT_AR + (size_t)(b0 + row) * S_LEN * I_DIM + (size_t)(t + 1) * I_DIM + hcol] = nv;
      }
    }
    sync_lds();  // barrier B: x_{t+1} staged

    // ---- P5: gates-x kt0,kt1; prime next step's kt2,kt3 ----
    {
      long a0 = A8FRAG(0);
      GCHUNK(a0, 0); DMAC(0, 0);          // c8 kt0 -> c0' (next kt2)
      long a1 = A8FRAG(1);
      GCHUNK(a1, 1); DMAC(2048, 1);       // c9 kt1 -> c1' (next kt3)
    }
  }
}

extern "C" void kernel_launch(void* const* d_in, const int* in_sizes, int n_in,
                              void* d_out, int out_size, void* d_ws, size_t ws_size,
                              hipStream_t stream) {
  const float* x       = (const float*)d_in[0];
  const float* w_ih    = (const float*)d_in[1];
  const float* w_hh    = (const float*)d_in[2];
  const float* b_ih    = (const float*)d_in[3];
  const float* b_hh    = (const float*)d_in[4];
  const float* pit_w1  = (const float*)d_in[5];
  const float* pit_b1  = (const float*)d_in[6];
  const float* pit_w2  = (const float*)d_in[7];
  const float* pit_b2  = (const float*)d_in[8];
  const float* time_w1 = (const float*)d_in[9];
  const float* time_b1 = (const float*)d_in[10];
  const float* time_w2 = (const float*)d_in[11];
  const float* time_b2 = (const float*)d_in[12];
  const float* ar_w1   = (const float*)d_in[13];
  const float* ar_b1   = (const float*)d_in[14];
  const float* ar_w2   = (const float*)d_in[15];
  const float* ar_b2   = (const float*)d_in[16];
  unsigned char* ws8   = (unsigned char*)d_ws;
  float* out           = (float*)d_out;

  prep_kernel<<<dim3((PREP_N + 255) / 256), dim3(256), 0, stream>>>(
      w_ih, w_hh, pit_w1, time_w1, ar_w1, ar_w2, ws8);
  rnn_kernel<<<dim3(16), dim3(NT), 0, stream>>>(
      x, b_ih, b_hh, pit_b1, pit_w2, pit_b2,
      time_w1, time_b1, time_w2, time_b2,
      ar_w1, ar_b1, ar_b2, ws8, out);
}

// Round 18
// 3428.966 us; speedup vs baseline: 1.3267x; 1.3267x over previous
//
#include <hip/hip_runtime.h>
#include <hip/hip_bf16.h>
#include <hip/hip_fp8.h>

// ---------------------------------------------------------------------------
// UnifiedModelRNN: B=256,S=512,I=64,H=256. 16 blocks x 512 threads (8 waves,
// 2/SIMD); block g owns batch rows [16g,16g+16). No grid sync.
// R18 = R17 with the head-weight LDS staging copy fixed (R17 copied 8 bytes
// per 16-byte stride -> half of pit8/tim8 was garbage -> absmax 24).
//  * Single fp8 [x|h] activation buffer A_f8 (bf16 h path deleted). Heads use
//    fp8 MFMA with LDS-RESIDENT fp8 pit/tim weights (fp8-head accuracy
//    proven by R15's pass at absmax 0.0039).
//  * Gate stream (40KB/wave/step, kt2..kt9,kt0,kt1): 12 chunks/step:
//    c0..c7 = kt2..kt9 (4 ops), c8..c11 = kt0a,kt0b,kt1a,kt1b (2 ops).
//    3-slot ring (8x3x4KB = 96KB), slot = c mod 3, TWO chunks in flight:
//    consume c (audited vmcnt = ops(c+1)+ops(c+2): 8,8,8,8,8,8,6,4,4,4,6,8)
//    -> MFMAs -> lgkmcnt(0) -> issue c+3 into the same slot. Interleaved
//    stores/x-loads only over-wait (safe).
//  * offset=0 exact-pointer DMAs (imm-offset arg corrupts LDS dst, R10-13).
//  * ar path stays bf16/f32 (xo_lds, ar1_lds, arw) for output accuracy.
//  * lgkm-only barriers; c-state f32 in registers.
// ---------------------------------------------------------------------------

typedef float f32x4 __attribute__((ext_vector_type(4)));
typedef short s16x8 __attribute__((ext_vector_type(8)));

#define S_LEN 512
#define I_DIM 64
#define NT    512

// ws byte offsets
#define WSTRIDE8 40960    // bytes per wave fp8 gate stream (80 frags x 512B)
#define WSB_P8   327680   // fp8 pit_w1: 32 frags x 512B = 16KB
#define WSB_T8   344064   // fp8 time_w1[:, :256]: 16KB
#define WSB_BF   360448   // bf16 region (u16 elems): arx 4096, ar2 4096
#define PREP_N   368640   // 360448 fp8 bytes + 8192 bf16 elems

#define OUT_PIT  0
#define OUT_TIME 131072
#define OUT_AR   262144

#define AF8 336   // fp8 [x(64)|h(256)] row stride (bytes)
#define XLD 72

__device__ __forceinline__ float sigf(float x) {
  return 1.0f / (1.0f + __expf(-x));
}
__device__ __forceinline__ float tanh_fast(float x) {
  float c = fminf(fmaxf(x, -15.0f), 15.0f);
  float e = __expf(2.0f * c);
  return (e - 1.0f) / (e + 1.0f);
}
__device__ __forceinline__ unsigned short f2bf(float f) {
  __hip_bfloat16 h = __float2bfloat16(f);
  return *reinterpret_cast<unsigned short*>(&h);
}
__device__ __forceinline__ unsigned char f2f8(float v) {
  __hip_fp8_e4m3 q(v);
  return *reinterpret_cast<unsigned char*>(&q);
}
// LDS-only barrier: does NOT drain vmcnt -> DMA stays in flight.
__device__ __forceinline__ void sync_lds() {
  asm volatile("s_waitcnt lgkmcnt(0)" ::: "memory");
  __builtin_amdgcn_s_barrier();
  asm volatile("" ::: "memory");
}
// 16B/lane global->LDS DMA, offset=0, exact pointers (proven form).
__device__ __forceinline__ void gld16(const void* g, void* l) {
  __builtin_amdgcn_global_load_lds(
      (const __attribute__((address_space(1))) unsigned int*)g,
      (__attribute__((address_space(3))) unsigned int*)l, 16, 0, 0);
}

__global__ void prep_kernel(const float* __restrict__ w_ih,
                            const float* __restrict__ w_hh,
                            const float* __restrict__ pit_w1,
                            const float* __restrict__ time_w1,
                            const float* __restrict__ ar_w1,
                            const float* __restrict__ ar_w2,
                            unsigned char* __restrict__ ws8) {
  int idx = blockIdx.x * 256 + threadIdx.x;
  if (idx >= PREP_N) return;
  if (idx < WSB_P8) {
    // fp8 gate byte (same layout as R14)
    int w  = idx / WSTRIDE8;
    int p8 = idx - w * WSTRIDE8;     // 0..40959
    int f  = p8 >> 9;                // frag 0..79
    int b  = p8 & 511;
    int lane = b >> 3, e = b & 7;
    int lrow = lane & 15, lgrp = lane >> 4;
    int ktidx = f >> 3, qm = f & 7;
    int kt = (ktidx < 8) ? ktidx + 2 : ktidx - 8;   // kt2..kt9,kt0,kt1
    int row = (qm >> 1) * 256 + w * 32 + (qm & 1) * 16 + lrow;
    int col = kt * 32 + lgrp * 8 + e;
    float v = (col < I_DIM) ? w_ih[row * I_DIM + col]
                            : w_hh[row * 256 + col - I_DIM];
    ws8[idx] = f2f8(v);
  } else if (idx < WSB_T8) {
    // fp8 pit_w1 frag (wv*8+kt)
    int p = idx - WSB_P8;
    int f = p >> 9, b = p & 511;
    int wv = f >> 3, kt = f & 7;
    int lane = b >> 3, e = b & 7;
    int lrow = lane & 15, lgrp = lane >> 4;
    ws8[idx] = f2f8(pit_w1[(wv * 16 + lrow) * 256 + kt * 32 + lgrp * 8 + e]);
  } else if (idx < WSB_BF) {
    // fp8 time_w1[:, :256] frag
    int p = idx - WSB_T8;
    int f = p >> 9, b = p & 511;
    int wv = f >> 3, kt = f & 7;
    int lane = b >> 3, e = b & 7;
    int lrow = lane & 15, lgrp = lane >> 4;
    ws8[idx] = f2f8(time_w1[(wv * 16 + lrow) * 257 + kt * 32 + lgrp * 8 + e]);
  } else {
    // bf16 element: arx then ar2
    int e2 = idx - WSB_BF;           // 0..8191
    int lane = (e2 >> 3) & 63;
    int e    = e2 & 7;
    int lrow = lane & 15, lgrp = lane >> 4;
    float v;
    if (e2 < 4096) {
      int f = e2 >> 9, wv = f >> 1, kt = f & 1;
      v = ar_w1[(wv * 16 + lrow) * 66 + 2 + kt * 32 + lgrp * 8 + e];
    } else {
      int f = (e2 - 4096) >> 9, wv = f >> 1, kt = f & 1;
      v = ar_w2[(wv * 16 + lrow) * 64 + kt * 32 + lgrp * 8 + e];
    }
    ((unsigned short*)(ws8 + WSB_BF))[e2] = f2bf(v);
  }
}

// fp8 A-frag from A_f8 (byte cols): 8 bytes/lane.
#define A8FRAG(kt) (*(const long*)&A_f8[lrow][(kt) * 32 + 8 * lgrp])

// DMA a 4-op (4KB) chunk / 2-op (2KB) chunk into stg8[wave][slot].
#define DMA4F(byteoff, slot)                                                   \
  do {                                                                         \
    const unsigned char* g_ = wg8l + (byteoff);                                \
    gld16(g_,        &stg8[wave][slot][0]);                                    \
    gld16(g_ + 1024, &stg8[wave][slot][1024]);                                 \
    gld16(g_ + 2048, &stg8[wave][slot][2048]);                                 \
    gld16(g_ + 3072, &stg8[wave][slot][3072]);                                 \
  } while (0)
#define DMA2F(byteoff, slot)                                                   \
  do {                                                                         \
    const unsigned char* g_ = wg8l + (byteoff);                                \
    gld16(g_,        &stg8[wave][slot][0]);                                    \
    gld16(g_ + 1024, &stg8[wave][slot][1024]);                                 \
  } while (0)

// Consume full gate chunk (8 frags qm=0..7) with fp8 A-frag af into acc2[qm].
#define GCHUNK8(af, slot, N)                                                   \
  do {                                                                         \
    asm volatile("s_waitcnt vmcnt(" #N ")" ::: "memory");                      \
    _Pragma("unroll")                                                          \
    for (int s_ = 0; s_ < 8; ++s_) {                                           \
      long b_ = *(const long*)&stg8[wave][slot][s_ * 512 + lane * 8];          \
      acc2[s_] = __builtin_amdgcn_mfma_f32_16x16x32_fp8_fp8(                   \
          (af), b_, acc2[s_], 0, 0, 0);                                        \
    }                                                                          \
    asm volatile("s_waitcnt lgkmcnt(0)" ::: "memory");                         \
  } while (0)
// Consume half gate chunk (4 frags) into acc2[qb..qb+3].
#define GHALF4(af, slot, N, qb)                                                \
  do {                                                                         \
    asm volatile("s_waitcnt vmcnt(" #N ")" ::: "memory");                      \
    _Pragma("unroll")                                                          \
    for (int s_ = 0; s_ < 4; ++s_) {                                           \
      long b_ = *(const long*)&stg8[wave][slot][s_ * 512 + lane * 8];          \
      acc2[(qb) + s_] = __builtin_amdgcn_mfma_f32_16x16x32_fp8_fp8(            \
          (af), b_, acc2[(qb) + s_], 0, 0, 0);                                 \
    }                                                                          \
    asm volatile("s_waitcnt lgkmcnt(0)" ::: "memory");                         \
  } while (0)

__global__ __launch_bounds__(NT, 2) void rnn_kernel(
    const float* __restrict__ x,
    const float* __restrict__ b_ih, const float* __restrict__ b_hh,
    const float* __restrict__ pit_b1, const float* __restrict__ pit_w2,
    const float* __restrict__ pit_b2,
    const float* __restrict__ time_w1, const float* __restrict__ time_b1,
    const float* __restrict__ time_w2, const float* __restrict__ time_b2,
    const float* __restrict__ ar_w1, const float* __restrict__ ar_b1,
    const float* __restrict__ ar_b2,
    const unsigned char* __restrict__ ws8,
    float* __restrict__ out)
{
  __shared__ __align__(16) unsigned char  A_f8[16][AF8];     // fp8 [x|h]
  __shared__ __align__(16) unsigned short xo_lds[16][XLD];   // x_orig[t] bf16
  __shared__ __align__(16) unsigned short ar1_lds[16][XLD];  // relu(ar1) bf16
  __shared__ __align__(16) unsigned char  pit8_lds[16384];   // fp8 pit_w1
  __shared__ __align__(16) unsigned char  tim8_lds[16384];   // fp8 time_w1
  __shared__ __align__(16) unsigned char  stg8[8][3][4096];  // DMA ring (96 KB)
  __shared__ float pitp[4][16];
  __shared__ float timep[4][16];

  const int tid  = threadIdx.x;
  const int wave = tid >> 6;
  const int lane = tid & 63;
  const int lrow = lane & 15;
  const int lgrp = lane >> 4;
  const int b0   = blockIdx.x * 16;
  const int hcol = (wave & 3) * 16 + lrow;
  const unsigned char* wg8l = ws8 + wave * WSTRIDE8 + lane * 16;  // DMA base
  const unsigned char* wg8  = ws8 + wave * WSTRIDE8;              // frag reads
  const unsigned short* wsb = (const unsigned short*)(ws8 + WSB_BF);

  // ---- one-time LDS staging: fp8 pit/tim weights (FIXED: 8B stride copy) ----
  for (int c = tid; c < 2048; c += NT) {
    *(long*)&pit8_lds[c * 8] = *(const long*)&ws8[WSB_P8 + c * 8];
    *(long*)&tim8_lds[c * 8] = *(const long*)&ws8[WSB_T8 + c * 8];
  }
  for (int i = tid; i < 16 * AF8; i += NT) (&A_f8[0][0])[i] = 0;

  // ---- role constants ----
  float gbias[8];
#pragma unroll
  for (int qm = 0; qm < 8; ++qm) {
    int g = (qm >> 1) * 256 + wave * 32 + (qm & 1) * 16 + lrow;
    gbias[qm] = b_ih[g] + b_hh[g];
  }
  s16x8 arw[2];
  float pb1v = 0, pw2v = 0, tb1v = 0, tw2v = 0, twlv = 0;
  float ab1v = 0, arpv = 0, artv = 0, ab2v = 0;
  if (wave < 4) {
    arw[0] = *(const s16x8*)&wsb[((wave & 3) * 2 + 0) * 512 + lane * 8];
    arw[1] = *(const s16x8*)&wsb[((wave & 3) * 2 + 1) * 512 + lane * 8];
    pb1v = pit_b1[hcol]; pw2v = pit_w2[hcol];
    ab1v = ar_b1[hcol];  arpv = ar_w1[hcol * 66]; artv = ar_w1[hcol * 66 + 1];
  } else {
    arw[0] = *(const s16x8*)&wsb[4096 + ((wave & 3) * 2 + 0) * 512 + lane * 8];
    arw[1] = *(const s16x8*)&wsb[4096 + ((wave & 3) * 2 + 1) * 512 + lane * 8];
    tb1v = time_b1[hcol]; tw2v = time_w2[hcol];
    twlv = time_w1[hcol * 257 + 256]; ab2v = ar_b2[hcol];
  }
  const float pb2 = pit_b2[0], tb2 = time_b2[0];

  // ---- stage x[:,0,:] (fp8), write ar_out[:,0,:] ----
  const int srow = tid >> 5;
  const int sc2  = (tid & 31) * 2;
  const size_t xbase = (size_t)(b0 + srow) * S_LEN * I_DIM + sc2;
  float2 xpre = *reinterpret_cast<const float2*>(&x[xbase]);
  __syncthreads();
  A_f8[srow][sc2]     = f2f8(xpre.x);
  A_f8[srow][sc2 + 1] = f2f8(xpre.y);
  *reinterpret_cast<float2*>(&out[OUT_AR + xbase]) = xpre;

  float cst[2][4];
#pragma unroll
  for (int m = 0; m < 2; ++m)
#pragma unroll
    for (int r = 0; r < 4; ++r) cst[m][r] = 0.0f;
  __syncthreads();

  // ---- prologue: gates(0) = bias + x0-part (h=0); kt0 frags 64+, kt1 72+ ----
  f32x4 acc2[8];
#pragma unroll
  for (int qm = 0; qm < 8; ++qm) {
    f32x4 tv; tv[0] = tv[1] = tv[2] = tv[3] = gbias[qm];
    acc2[qm] = tv;
  }
  {
    long a0 = A8FRAG(0);
#pragma unroll
    for (int qm = 0; qm < 8; ++qm) {
      long b = *(const long*)(wg8 + (64 + qm) * 512 + lane * 8);
      acc2[qm] = __builtin_amdgcn_mfma_f32_16x16x32_fp8_fp8(a0, b, acc2[qm], 0, 0, 0);
    }
    long a1 = A8FRAG(1);
#pragma unroll
    for (int qm = 0; qm < 8; ++qm) {
      long b = *(const long*)(wg8 + (72 + qm) * 512 + lane * 8);
      acc2[qm] = __builtin_amdgcn_mfma_f32_16x16x32_fp8_fp8(a1, b, acc2[qm], 0, 0, 0);
    }
  }
  // drain prologue plain loads; prime ring: c0=kt2(s0), c1=kt3(s1), c2=kt4(s2)
  asm volatile("s_waitcnt vmcnt(0)" ::: "memory");
  DMA4F(0, 0);
  DMA4F(4096, 1);
  DMA4F(8192, 2);

  // =========================== time loop ===========================
  for (int t = 0; t < S_LEN; ++t) {
    // ---- P0: xo stage, x prefetch, LSTM -> h (fp8 only) ----
    xo_lds[srow][sc2]     = f2bf(xpre.x);
    xo_lds[srow][sc2 + 1] = f2bf(xpre.y);
    if (t + 1 < S_LEN)
      xpre = *reinterpret_cast<const float2*>(&x[xbase + (size_t)(t + 1) * I_DIM]);

#pragma unroll
    for (int m = 0; m < 2; ++m)
#pragma unroll
      for (int r = 0; r < 4; ++r) {
        float ig = sigf(acc2[0 + m][r]);
        float fg = sigf(acc2[2 + m][r]);
        float gg = tanh_fast(acc2[4 + m][r]);
        float og = sigf(acc2[6 + m][r]);
        float c  = fg * cst[m][r] + ig * gg;
        cst[m][r] = c;
        A_f8[lgrp * 4 + r][64 + wave * 32 + m * 16 + lrow] = f2f8(og * tanh_fast(c));
      }
#pragma unroll
    for (int qm = 0; qm < 8; ++qm) {
      f32x4 tv; tv[0] = tv[1] = tv[2] = tv[3] = gbias[qm];
      acc2[qm] = tv;
    }
    sync_lds();  // barrier A: h + xo ready

    // ---- P1: heads (fp8, LDS weights); pit reduce; gates c0..c3 (kt2-5) ----
    long hfr8[8];
#pragma unroll
    for (int k = 0; k < 8; ++k)
      hfr8[k] = *(const long*)&A_f8[lrow][64 + k * 32 + 8 * lgrp];

    f32x4 hacc;
    {
      float hb = (wave < 4) ? pb1v : tb1v;
      hacc[0] = hacc[1] = hacc[2] = hacc[3] = hb;
      const unsigned char* hbp = (wave < 4) ? pit8_lds : tim8_lds;
#pragma unroll
      for (int kt = 0; kt < 8; ++kt) {
        long bH = *(const long*)&hbp[((wave & 3) * 8 + kt) * 512 + lane * 8];
        hacc = __builtin_amdgcn_mfma_f32_16x16x32_fp8_fp8(hfr8[kt], bH, hacc, 0, 0, 0);
      }
    }
    if (wave < 4) {  // pit partial reduce
      float v[4];
#pragma unroll
      for (int r = 0; r < 4; ++r) v[r] = fmaxf(hacc[r], 0.0f) * pw2v;
#pragma unroll
      for (int off = 1; off < 16; off <<= 1)
#pragma unroll
        for (int r = 0; r < 4; ++r) v[r] += __shfl_xor(v[r], off);
      if (lrow == 0) {
#pragma unroll
        for (int r = 0; r < 4; ++r) pitp[wave][lgrp * 4 + r] = v[r];
      }
    }
    GCHUNK8(hfr8[0], 0, 8); DMA4F(12288, 0);  // c0 kt2 -> c3 (kt5)
    GCHUNK8(hfr8[1], 1, 8); DMA4F(16384, 1);  // c1 kt3 -> c4 (kt6)
    GCHUNK8(hfr8[2], 2, 8); DMA4F(20480, 2);  // c2 kt4 -> c5 (kt7)
    GCHUNK8(hfr8[3], 0, 8); DMA4F(24576, 0);  // c3 kt5 -> c6 (kt8)
    sync_lds();  // barrier 1: pit partials ready

    // ---- P2: pv; time finish / ar1-x; pit out; c4,c5 (kt6,7) ----
    float pv[4];
#pragma unroll
    for (int r = 0; r < 4; ++r) {
      int row = lgrp * 4 + r;
      pv[r] = pitp[0][row] + pitp[1][row] + pitp[2][row] + pitp[3][row] + pb2;
    }
    f32x4 aracc;
    if (wave < 4) {
      aracc[0] = aracc[1] = aracc[2] = aracc[3] = ab1v;
#pragma unroll
      for (int kt = 0; kt < 2; ++kt) {
        s16x8 aX = *(const s16x8*)&xo_lds[lrow][kt * 32 + 8 * lgrp];
        aracc = __builtin_amdgcn_mfma_f32_16x16x32_bf16(aX, arw[kt], aracc, 0, 0, 0);
      }
      if (wave == 0 && lane < 16) {
        float pvs = pitp[0][lane] + pitp[1][lane] + pitp[2][lane] + pitp[3][lane] + pb2;
        out[OUT_PIT + (size_t)(b0 + lane) * S_LEN + t] = pvs;
      }
    } else {
      float v[4];
#pragma unroll
      for (int r = 0; r < 4; ++r)
        v[r] = fmaxf(hacc[r] + pv[r] * twlv, 0.0f) * tw2v;
#pragma unroll
      for (int off = 1; off < 16; off <<= 1)
#pragma unroll
        for (int r = 0; r < 4; ++r) v[r] += __shfl_xor(v[r], off);
      if (lrow == 0) {
#pragma unroll
        for (int r = 0; r < 4; ++r) timep[wave & 3][lgrp * 4 + r] = v[r];
      }
    }
    GCHUNK8(hfr8[4], 1, 8); DMA4F(28672, 1);  // c4 kt6 -> c7 (kt9)
    GCHUNK8(hfr8[5], 2, 8); DMA2F(32768, 2);  // c5 kt7 -> c8 (kt0a)
    sync_lds();  // barrier 2: time partials ready

    // ---- P3: tv; ar1 finish; time out; c6,c7 (kt8,9) ----
    float tvv[4];
#pragma unroll
    for (int r = 0; r < 4; ++r) {
      int row = lgrp * 4 + r;
      tvv[r] = timep[0][row] + timep[1][row] + timep[2][row] + timep[3][row] + tb2;
    }
    if (wave < 4) {
#pragma unroll
      for (int r = 0; r < 4; ++r) {
        float a1 = aracc[r] + pv[r] * arpv + tvv[r] * artv;
        ar1_lds[lgrp * 4 + r][hcol] = f2bf(fmaxf(a1, 0.0f));
      }
    } else if (wave == 4 && lane < 16) {
      float tvs = timep[0][lane] + timep[1][lane] + timep[2][lane] + timep[3][lane] + tb2;
      out[OUT_TIME + (size_t)(b0 + lane) * S_LEN + t] = tvs;
    }
    GCHUNK8(hfr8[6], 0, 6); DMA2F(34816, 0);  // c6 kt8 -> c9 (kt0b)
    GCHUNK8(hfr8[7], 1, 4); DMA2F(36864, 1);  // c7 kt9 -> c10 (kt1a)
    sync_lds();  // barrier 3: ar1 ready

    // ---- P4: ar2 -> x_{t+1} (waves 4-7), fp8 ----
    if (wave >= 4) {
      f32x4 nacc;
      nacc[0] = nacc[1] = nacc[2] = nacc[3] = ab2v;
#pragma unroll
      for (int kt = 0; kt < 2; ++kt) {
        s16x8 aR = *(const s16x8*)&ar1_lds[lrow][kt * 32 + 8 * lgrp];
        nacc = __builtin_amdgcn_mfma_f32_16x16x32_bf16(aR, arw[kt], nacc, 0, 0, 0);
      }
#pragma unroll
      for (int r = 0; r < 4; ++r) {
        int row = lgrp * 4 + r;
        float nv = nacc[r];
        A_f8[row][hcol] = f2f8(nv);
        if (t < S_LEN - 1)
          out[OUT_AR + (size_t)(b0 + row) * S_LEN * I_DIM + (size_t)(t + 1) * I_DIM + hcol] = nv;
      }
    }
    sync_lds();  // barrier B: x_{t+1} staged

    // ---- P5: gates-x c8..c11 (kt0a,b / kt1a,b); prime next step ----
    {
      long a0 = A8FRAG(0);
      GHALF4(a0, 2, 4, 0); DMA2F(38912, 2);   // c8 kt0a -> c11 (kt1b)
      GHALF4(a0, 0, 4, 4); DMA4F(0, 0);       // c9 kt0b -> c0' (kt2)
      long a1 = A8FRAG(1);
      GHALF4(a1, 1, 6, 0); DMA4F(4096, 1);    // c10 kt1a -> c1' (kt3)
      GHALF4(a1, 2, 8, 4); DMA4F(8192, 2);    // c11 kt1b -> c2' (kt4)
    }
  }
}

extern "C" void kernel_launch(void* const* d_in, const int* in_sizes, int n_in,
                              void* d_out, int out_size, void* d_ws, size_t ws_size,
                              hipStream_t stream) {
  const float* x       = (const float*)d_in[0];
  const float* w_ih    = (const float*)d_in[1];
  const float* w_hh    = (const float*)d_in[2];
  const float* b_ih    = (const float*)d_in[3];
  const float* b_hh    = (const float*)d_in[4];
  const float* pit_w1  = (const float*)d_in[5];
  const float* pit_b1  = (const float*)d_in[6];
  const float* pit_w2  = (const float*)d_in[7];
  const float* pit_b2  = (const float*)d_in[8];
  const float* time_w1 = (const float*)d_in[9];
  const float* time_b1 = (const float*)d_in[10];
  const float* time_w2 = (const float*)d_in[11];
  const float* time_b2 = (const float*)d_in[12];
  const float* ar_w1   = (const float*)d_in[13];
  const float* ar_b1   = (const float*)d_in[14];
  const float* ar_w2   = (const float*)d_in[15];
  const float* ar_b2   = (const float*)d_in[16];
  unsigned char* ws8   = (unsigned char*)d_ws;
  float* out           = (float*)d_out;

  prep_kernel<<<dim3((PREP_N + 255) / 256), dim3(256), 0, stream>>>(
      w_ih, w_hh, pit_w1, time_w1, ar_w1, ar_w2, ws8);
  rnn_kernel<<<dim3(16), dim3(NT), 0, stream>>>(
      x, b_ih, b_hh, pit_b1, pit_w2, pit_b2,
      time_w1, time_b1, time_w2, time_b2,
      ar_w1, ar_b1, ar_b2, ws8, out);
}

// Round 19
// 3394.360 us; speedup vs baseline: 1.3402x; 1.0102x over previous
//
#include <hip/hip_runtime.h>
#include <hip/hip_bf16.h>
#include <hip/hip_fp8.h>

// ---------------------------------------------------------------------------
// UnifiedModelRNN: B=256,S=512,I=64,H=256. 16 blocks x 512 threads (8 waves,
// 2/SIMD); block g owns batch rows [16g,16g+16). No grid sync.
// R19 = R18 with critical-path polish (DMA ring/protocol untouched):
//  * Head MFMA chain split into two independent 4-chains (hacc0+hacc1).
//  * pit/time partials stored TRANSPOSED (pitpT[16][4]) -> consumers read one
//    ds_read_b128 per row instead of 4 ds_read_b32 (-24 LDS ops/thread/step).
//  * All else identical to R18: fp8 gates+heads, 3-slot ring (96KB), audited
//    vmcnt ladder, offset=0 exact-pointer DMAs, lgkm-only barriers, ar path
//    bf16/f32, c-state f32 in registers.
// ---------------------------------------------------------------------------

typedef float f32x4 __attribute__((ext_vector_type(4)));
typedef short s16x8 __attribute__((ext_vector_type(8)));

#define S_LEN 512
#define I_DIM 64
#define NT    512

// ws byte offsets
#define WSTRIDE8 40960    // bytes per wave fp8 gate stream (80 frags x 512B)
#define WSB_P8   327680   // fp8 pit_w1: 32 frags x 512B = 16KB
#define WSB_T8   344064   // fp8 time_w1[:, :256]: 16KB
#define WSB_BF   360448   // bf16 region (u16 elems): arx 4096, ar2 4096
#define PREP_N   368640   // 360448 fp8 bytes + 8192 bf16 elems

#define OUT_PIT  0
#define OUT_TIME 131072
#define OUT_AR   262144

#define AF8 336   // fp8 [x(64)|h(256)] row stride (bytes)
#define XLD 72

__device__ __forceinline__ float sigf(float x) {
  return 1.0f / (1.0f + __expf(-x));
}
__device__ __forceinline__ float tanh_fast(float x) {
  float c = fminf(fmaxf(x, -15.0f), 15.0f);
  float e = __expf(2.0f * c);
  return (e - 1.0f) / (e + 1.0f);
}
__device__ __forceinline__ unsigned short f2bf(float f) {
  __hip_bfloat16 h = __float2bfloat16(f);
  return *reinterpret_cast<unsigned short*>(&h);
}
__device__ __forceinline__ unsigned char f2f8(float v) {
  __hip_fp8_e4m3 q(v);
  return *reinterpret_cast<unsigned char*>(&q);
}
// LDS-only barrier: does NOT drain vmcnt -> DMA stays in flight.
__device__ __forceinline__ void sync_lds() {
  asm volatile("s_waitcnt lgkmcnt(0)" ::: "memory");
  __builtin_amdgcn_s_barrier();
  asm volatile("" ::: "memory");
}
// 16B/lane global->LDS DMA, offset=0, exact pointers (proven form).
__device__ __forceinline__ void gld16(const void* g, void* l) {
  __builtin_amdgcn_global_load_lds(
      (const __attribute__((address_space(1))) unsigned int*)g,
      (__attribute__((address_space(3))) unsigned int*)l, 16, 0, 0);
}

__global__ void prep_kernel(const float* __restrict__ w_ih,
                            const float* __restrict__ w_hh,
                            const float* __restrict__ pit_w1,
                            const float* __restrict__ time_w1,
                            const float* __restrict__ ar_w1,
                            const float* __restrict__ ar_w2,
                            unsigned char* __restrict__ ws8) {
  int idx = blockIdx.x * 256 + threadIdx.x;
  if (idx >= PREP_N) return;
  if (idx < WSB_P8) {
    // fp8 gate byte (same layout as R14/R18)
    int w  = idx / WSTRIDE8;
    int p8 = idx - w * WSTRIDE8;     // 0..40959
    int f  = p8 >> 9;                // frag 0..79
    int b  = p8 & 511;
    int lane = b >> 3, e = b & 7;
    int lrow = lane & 15, lgrp = lane >> 4;
    int ktidx = f >> 3, qm = f & 7;
    int kt = (ktidx < 8) ? ktidx + 2 : ktidx - 8;   // kt2..kt9,kt0,kt1
    int row = (qm >> 1) * 256 + w * 32 + (qm & 1) * 16 + lrow;
    int col = kt * 32 + lgrp * 8 + e;
    float v = (col < I_DIM) ? w_ih[row * I_DIM + col]
                            : w_hh[row * 256 + col - I_DIM];
    ws8[idx] = f2f8(v);
  } else if (idx < WSB_T8) {
    // fp8 pit_w1 frag (wv*8+kt)
    int p = idx - WSB_P8;
    int f = p >> 9, b = p & 511;
    int wv = f >> 3, kt = f & 7;
    int lane = b >> 3, e = b & 7;
    int lrow = lane & 15, lgrp = lane >> 4;
    ws8[idx] = f2f8(pit_w1[(wv * 16 + lrow) * 256 + kt * 32 + lgrp * 8 + e]);
  } else if (idx < WSB_BF) {
    // fp8 time_w1[:, :256] frag
    int p = idx - WSB_T8;
    int f = p >> 9, b = p & 511;
    int wv = f >> 3, kt = f & 7;
    int lane = b >> 3, e = b & 7;
    int lrow = lane & 15, lgrp = lane >> 4;
    ws8[idx] = f2f8(time_w1[(wv * 16 + lrow) * 257 + kt * 32 + lgrp * 8 + e]);
  } else {
    // bf16 element: arx then ar2
    int e2 = idx - WSB_BF;           // 0..8191
    int lane = (e2 >> 3) & 63;
    int e    = e2 & 7;
    int lrow = lane & 15, lgrp = lane >> 4;
    float v;
    if (e2 < 4096) {
      int f = e2 >> 9, wv = f >> 1, kt = f & 1;
      v = ar_w1[(wv * 16 + lrow) * 66 + 2 + kt * 32 + lgrp * 8 + e];
    } else {
      int f = (e2 - 4096) >> 9, wv = f >> 1, kt = f & 1;
      v = ar_w2[(wv * 16 + lrow) * 64 + kt * 32 + lgrp * 8 + e];
    }
    ((unsigned short*)(ws8 + WSB_BF))[e2] = f2bf(v);
  }
}

// fp8 A-frag from A_f8 (byte cols): 8 bytes/lane.
#define A8FRAG(kt) (*(const long*)&A_f8[lrow][(kt) * 32 + 8 * lgrp])

// DMA a 4-op (4KB) chunk / 2-op (2KB) chunk into stg8[wave][slot].
#define DMA4F(byteoff, slot)                                                   \
  do {                                                                         \
    const unsigned char* g_ = wg8l + (byteoff);                                \
    gld16(g_,        &stg8[wave][slot][0]);                                    \
    gld16(g_ + 1024, &stg8[wave][slot][1024]);                                 \
    gld16(g_ + 2048, &stg8[wave][slot][2048]);                                 \
    gld16(g_ + 3072, &stg8[wave][slot][3072]);                                 \
  } while (0)
#define DMA2F(byteoff, slot)                                                   \
  do {                                                                         \
    const unsigned char* g_ = wg8l + (byteoff);                                \
    gld16(g_,        &stg8[wave][slot][0]);                                    \
    gld16(g_ + 1024, &stg8[wave][slot][1024]);                                 \
  } while (0)

// Consume full gate chunk (8 frags qm=0..7) with fp8 A-frag af into acc2[qm].
#define GCHUNK8(af, slot, N)                                                   \
  do {                                                                         \
    asm volatile("s_waitcnt vmcnt(" #N ")" ::: "memory");                      \
    _Pragma("unroll")                                                          \
    for (int s_ = 0; s_ < 8; ++s_) {                                           \
      long b_ = *(const long*)&stg8[wave][slot][s_ * 512 + lane * 8];          \
      acc2[s_] = __builtin_amdgcn_mfma_f32_16x16x32_fp8_fp8(                   \
          (af), b_, acc2[s_], 0, 0, 0);                                        \
    }                                                                          \
    asm volatile("s_waitcnt lgkmcnt(0)" ::: "memory");                         \
  } while (0)
// Consume half gate chunk (4 frags) into acc2[qb..qb+3].
#define GHALF4(af, slot, N, qb)                                                \
  do {                                                                         \
    asm volatile("s_waitcnt vmcnt(" #N ")" ::: "memory");                      \
    _Pragma("unroll")                                                          \
    for (int s_ = 0; s_ < 4; ++s_) {                                           \
      long b_ = *(const long*)&stg8[wave][slot][s_ * 512 + lane * 8];          \
      acc2[(qb) + s_] = __builtin_amdgcn_mfma_f32_16x16x32_fp8_fp8(            \
          (af), b_, acc2[(qb) + s_], 0, 0, 0);                                 \
    }                                                                          \
    asm volatile("s_waitcnt lgkmcnt(0)" ::: "memory");                         \
  } while (0)

__global__ __launch_bounds__(NT, 2) void rnn_kernel(
    const float* __restrict__ x,
    const float* __restrict__ b_ih, const float* __restrict__ b_hh,
    const float* __restrict__ pit_b1, const float* __restrict__ pit_w2,
    const float* __restrict__ pit_b2,
    const float* __restrict__ time_w1, const float* __restrict__ time_b1,
    const float* __restrict__ time_w2, const float* __restrict__ time_b2,
    const float* __restrict__ ar_w1, const float* __restrict__ ar_b1,
    const float* __restrict__ ar_b2,
    const unsigned char* __restrict__ ws8,
    float* __restrict__ out)
{
  __shared__ __align__(16) unsigned char  A_f8[16][AF8];     // fp8 [x|h]
  __shared__ __align__(16) unsigned short xo_lds[16][XLD];   // x_orig[t] bf16
  __shared__ __align__(16) unsigned short ar1_lds[16][XLD];  // relu(ar1) bf16
  __shared__ __align__(16) unsigned char  pit8_lds[16384];   // fp8 pit_w1
  __shared__ __align__(16) unsigned char  tim8_lds[16384];   // fp8 time_w1
  __shared__ __align__(16) unsigned char  stg8[8][3][4096];  // DMA ring (96 KB)
  __shared__ __align__(16) float pitpT[16][4];               // transposed partials
  __shared__ __align__(16) float timepT[16][4];

  const int tid  = threadIdx.x;
  const int wave = tid >> 6;
  const int lane = tid & 63;
  const int lrow = lane & 15;
  const int lgrp = lane >> 4;
  const int b0   = blockIdx.x * 16;
  const int hcol = (wave & 3) * 16 + lrow;
  const unsigned char* wg8l = ws8 + wave * WSTRIDE8 + lane * 16;  // DMA base
  const unsigned char* wg8  = ws8 + wave * WSTRIDE8;              // frag reads
  const unsigned short* wsb = (const unsigned short*)(ws8 + WSB_BF);

  // ---- one-time LDS staging: fp8 pit/tim weights (8B stride copy) ----
  for (int c = tid; c < 2048; c += NT) {
    *(long*)&pit8_lds[c * 8] = *(const long*)&ws8[WSB_P8 + c * 8];
    *(long*)&tim8_lds[c * 8] = *(const long*)&ws8[WSB_T8 + c * 8];
  }
  for (int i = tid; i < 16 * AF8; i += NT) (&A_f8[0][0])[i] = 0;

  // ---- role constants ----
  float gbias[8];
#pragma unroll
  for (int qm = 0; qm < 8; ++qm) {
    int g = (qm >> 1) * 256 + wave * 32 + (qm & 1) * 16 + lrow;
    gbias[qm] = b_ih[g] + b_hh[g];
  }
  s16x8 arw[2];
  float pb1v = 0, pw2v = 0, tb1v = 0, tw2v = 0, twlv = 0;
  float ab1v = 0, arpv = 0, artv = 0, ab2v = 0;
  if (wave < 4) {
    arw[0] = *(const s16x8*)&wsb[((wave & 3) * 2 + 0) * 512 + lane * 8];
    arw[1] = *(const s16x8*)&wsb[((wave & 3) * 2 + 1) * 512 + lane * 8];
    pb1v = pit_b1[hcol]; pw2v = pit_w2[hcol];
    ab1v = ar_b1[hcol];  arpv = ar_w1[hcol * 66]; artv = ar_w1[hcol * 66 + 1];
  } else {
    arw[0] = *(const s16x8*)&wsb[4096 + ((wave & 3) * 2 + 0) * 512 + lane * 8];
    arw[1] = *(const s16x8*)&wsb[4096 + ((wave & 3) * 2 + 1) * 512 + lane * 8];
    tb1v = time_b1[hcol]; tw2v = time_w2[hcol];
    twlv = time_w1[hcol * 257 + 256]; ab2v = ar_b2[hcol];
  }
  const float pb2 = pit_b2[0], tb2 = time_b2[0];

  // ---- stage x[:,0,:] (fp8), write ar_out[:,0,:] ----
  const int srow = tid >> 5;
  const int sc2  = (tid & 31) * 2;
  const size_t xbase = (size_t)(b0 + srow) * S_LEN * I_DIM + sc2;
  float2 xpre = *reinterpret_cast<const float2*>(&x[xbase]);
  __syncthreads();
  A_f8[srow][sc2]     = f2f8(xpre.x);
  A_f8[srow][sc2 + 1] = f2f8(xpre.y);
  *reinterpret_cast<float2*>(&out[OUT_AR + xbase]) = xpre;

  float cst[2][4];
#pragma unroll
  for (int m = 0; m < 2; ++m)
#pragma unroll
    for (int r = 0; r < 4; ++r) cst[m][r] = 0.0f;
  __syncthreads();

  // ---- prologue: gates(0) = bias + x0-part (h=0); kt0 frags 64+, kt1 72+ ----
  f32x4 acc2[8];
#pragma unroll
  for (int qm = 0; qm < 8; ++qm) {
    f32x4 tv; tv[0] = tv[1] = tv[2] = tv[3] = gbias[qm];
    acc2[qm] = tv;
  }
  {
    long a0 = A8FRAG(0);
#pragma unroll
    for (int qm = 0; qm < 8; ++qm) {
      long b = *(const long*)(wg8 + (64 + qm) * 512 + lane * 8);
      acc2[qm] = __builtin_amdgcn_mfma_f32_16x16x32_fp8_fp8(a0, b, acc2[qm], 0, 0, 0);
    }
    long a1 = A8FRAG(1);
#pragma unroll
    for (int qm = 0; qm < 8; ++qm) {
      long b = *(const long*)(wg8 + (72 + qm) * 512 + lane * 8);
      acc2[qm] = __builtin_amdgcn_mfma_f32_16x16x32_fp8_fp8(a1, b, acc2[qm], 0, 0, 0);
    }
  }
  // drain prologue plain loads; prime ring: c0=kt2(s0), c1=kt3(s1), c2=kt4(s2)
  asm volatile("s_waitcnt vmcnt(0)" ::: "memory");
  DMA4F(0, 0);
  DMA4F(4096, 1);
  DMA4F(8192, 2);

  // =========================== time loop ===========================
  for (int t = 0; t < S_LEN; ++t) {
    // ---- P0: xo stage, x prefetch, LSTM -> h (fp8 only) ----
    xo_lds[srow][sc2]     = f2bf(xpre.x);
    xo_lds[srow][sc2 + 1] = f2bf(xpre.y);
    if (t + 1 < S_LEN)
      xpre = *reinterpret_cast<const float2*>(&x[xbase + (size_t)(t + 1) * I_DIM]);

#pragma unroll
    for (int m = 0; m < 2; ++m)
#pragma unroll
      for (int r = 0; r < 4; ++r) {
        float ig = sigf(acc2[0 + m][r]);
        float fg = sigf(acc2[2 + m][r]);
        float gg = tanh_fast(acc2[4 + m][r]);
        float og = sigf(acc2[6 + m][r]);
        float c  = fg * cst[m][r] + ig * gg;
        cst[m][r] = c;
        A_f8[lgrp * 4 + r][64 + wave * 32 + m * 16 + lrow] = f2f8(og * tanh_fast(c));
      }
#pragma unroll
    for (int qm = 0; qm < 8; ++qm) {
      f32x4 tv; tv[0] = tv[1] = tv[2] = tv[3] = gbias[qm];
      acc2[qm] = tv;
    }
    sync_lds();  // barrier A: h + xo ready

    // ---- P1: heads (fp8, LDS weights, 2 ILP chains); pit reduce;
    //          gates c0..c3 (kt2-5) ----
    long hfr8[8];
#pragma unroll
    for (int k = 0; k < 8; ++k)
      hfr8[k] = *(const long*)&A_f8[lrow][64 + k * 32 + 8 * lgrp];

    f32x4 hacc;
    {
      float hb = (wave < 4) ? pb1v : tb1v;
      f32x4 h0, h1;
      h0[0] = h0[1] = h0[2] = h0[3] = hb;
      h1[0] = h1[1] = h1[2] = h1[3] = 0.0f;
      const unsigned char* hbp = (wave < 4) ? pit8_lds : tim8_lds;
#pragma unroll
      for (int kt = 0; kt < 4; ++kt) {
        long b0f = *(const long*)&hbp[((wave & 3) * 8 + 2 * kt) * 512 + lane * 8];
        long b1f = *(const long*)&hbp[((wave & 3) * 8 + 2 * kt + 1) * 512 + lane * 8];
        h0 = __builtin_amdgcn_mfma_f32_16x16x32_fp8_fp8(hfr8[2 * kt], b0f, h0, 0, 0, 0);
        h1 = __builtin_amdgcn_mfma_f32_16x16x32_fp8_fp8(hfr8[2 * kt + 1], b1f, h1, 0, 0, 0);
      }
#pragma unroll
      for (int r = 0; r < 4; ++r) hacc[r] = h0[r] + h1[r];
    }
    if (wave < 4) {  // pit partial reduce -> transposed store
      float v[4];
#pragma unroll
      for (int r = 0; r < 4; ++r) v[r] = fmaxf(hacc[r], 0.0f) * pw2v;
#pragma unroll
      for (int off = 1; off < 16; off <<= 1)
#pragma unroll
        for (int r = 0; r < 4; ++r) v[r] += __shfl_xor(v[r], off);
      if (lrow == 0) {
#pragma unroll
        for (int r = 0; r < 4; ++r) pitpT[lgrp * 4 + r][wave] = v[r];
      }
    }
    GCHUNK8(hfr8[0], 0, 8); DMA4F(12288, 0);  // c0 kt2 -> c3 (kt5)
    GCHUNK8(hfr8[1], 1, 8); DMA4F(16384, 1);  // c1 kt3 -> c4 (kt6)
    GCHUNK8(hfr8[2], 2, 8); DMA4F(20480, 2);  // c2 kt4 -> c5 (kt7)
    GCHUNK8(hfr8[3], 0, 8); DMA4F(24576, 0);  // c3 kt5 -> c6 (kt8)
    sync_lds();  // barrier 1: pit partials ready

    // ---- P2: pv (b128 reads); time finish / ar1-x; pit out; c4,c5 ----
    float pv[4];
#pragma unroll
    for (int r = 0; r < 4; ++r) {
      f32x4 pq = *(const f32x4*)&pitpT[lgrp * 4 + r][0];
      pv[r] = pq[0] + pq[1] + pq[2] + pq[3] + pb2;
    }
    f32x4 aracc;
    if (wave < 4) {
      aracc[0] = aracc[1] = aracc[2] = aracc[3] = ab1v;
#pragma unroll
      for (int kt = 0; kt < 2; ++kt) {
        s16x8 aX = *(const s16x8*)&xo_lds[lrow][kt * 32 + 8 * lgrp];
        aracc = __builtin_amdgcn_mfma_f32_16x16x32_bf16(aX, arw[kt], aracc, 0, 0, 0);
      }
      if (wave == 0 && lane < 16) {
        f32x4 pq = *(const f32x4*)&pitpT[lane][0];
        out[OUT_PIT + (size_t)(b0 + lane) * S_LEN + t] =
            pq[0] + pq[1] + pq[2] + pq[3] + pb2;
      }
    } else {
      float v[4];
#pragma unroll
      for (int r = 0; r < 4; ++r)
        v[r] = fmaxf(hacc[r] + pv[r] * twlv, 0.0f) * tw2v;
#pragma unroll
      for (int off = 1; off < 16; off <<= 1)
#pragma unroll
        for (int r = 0; r < 4; ++r) v[r] += __shfl_xor(v[r], off);
      if (lrow == 0) {
#pragma unroll
        for (int r = 0; r < 4; ++r) timepT[lgrp * 4 + r][wave & 3] = v[r];
      }
    }
    GCHUNK8(hfr8[4], 1, 8); DMA4F(28672, 1);  // c4 kt6 -> c7 (kt9)
    GCHUNK8(hfr8[5], 2, 8); DMA2F(32768, 2);  // c5 kt7 -> c8 (kt0a)
    sync_lds();  // barrier 2: time partials ready

    // ---- P3: tvv (b128 reads); ar1 finish; time out; c6,c7 ----
    float tvv[4];
#pragma unroll
    for (int r = 0; r < 4; ++r) {
      f32x4 tq = *(const f32x4*)&timepT[lgrp * 4 + r][0];
      tvv[r] = tq[0] + tq[1] + tq[2] + tq[3] + tb2;
    }
    if (wave < 4) {
#pragma unroll
      for (int r = 0; r < 4; ++r) {
        float a1 = aracc[r] + pv[r] * arpv + tvv[r] * artv;
        ar1_lds[lgrp * 4 + r][hcol] = f2bf(fmaxf(a1, 0.0f));
      }
    } else if (wave == 4 && lane < 16) {
      f32x4 tq = *(const f32x4*)&timepT[lane][0];
      out[OUT_TIME + (size_t)(b0 + lane) * S_LEN + t] =
          tq[0] + tq[1] + tq[2] + tq[3] + tb2;
    }
    GCHUNK8(hfr8[6], 0, 6); DMA2F(34816, 0);  // c6 kt8 -> c9 (kt0b)
    GCHUNK8(hfr8[7], 1, 4); DMA2F(36864, 1);  // c7 kt9 -> c10 (kt1a)
    sync_lds();  // barrier 3: ar1 ready

    // ---- P4: ar2 -> x_{t+1} (waves 4-7), fp8 ----
    if (wave >= 4) {
      f32x4 nacc;
      nacc[0] = nacc[1] = nacc[2] = nacc[3] = ab2v;
#pragma unroll
      for (int kt = 0; kt < 2; ++kt) {
        s16x8 aR = *(const s16x8*)&ar1_lds[lrow][kt * 32 + 8 * lgrp];
        nacc = __builtin_amdgcn_mfma_f32_16x16x32_bf16(aR, arw[kt], nacc, 0, 0, 0);
      }
#pragma unroll
      for (int r = 0; r < 4; ++r) {
        int row = lgrp * 4 + r;
        float nv = nacc[r];
        A_f8[row][hcol] = f2f8(nv);
        if (t < S_LEN - 1)
          out[OUT_AR + (size_t)(b0 + row) * S_LEN * I_DIM + (size_t)(t + 1) * I_DIM + hcol] = nv;
      }
    }
    sync_lds();  // barrier B: x_{t+1} staged

    // ---- P5: gates-x c8..c11 (kt0a,b / kt1a,b); prime next step ----
    {
      long a0 = A8FRAG(0);
      GHALF4(a0, 2, 4, 0); DMA2F(38912, 2);   // c8 kt0a -> c11 (kt1b)
      GHALF4(a0, 0, 4, 4); DMA4F(0, 0);       // c9 kt0b -> c0' (kt2)
      long a1 = A8FRAG(1);
      GHALF4(a1, 1, 6, 0); DMA4F(4096, 1);    // c10 kt1a -> c1' (kt3)
      GHALF4(a1, 2, 8, 4); DMA4F(8192, 2);    // c11 kt1b -> c2' (kt4)
    }
  }
}

extern "C" void kernel_launch(void* const* d_in, const int* in_sizes, int n_in,
                              void* d_out, int out_size, void* d_ws, size_t ws_size,
                              hipStream_t stream) {
  const float* x       = (const float*)d_in[0];
  const float* w_ih    = (const float*)d_in[1];
  const float* w_hh    = (const float*)d_in[2];
  const float* b_ih    = (const float*)d_in[3];
  const float* b_hh    = (const float*)d_in[4];
  const float* pit_w1  = (const float*)d_in[5];
  const float* pit_b1  = (const float*)d_in[6];
  const float* pit_w2  = (const float*)d_in[7];
  const float* pit_b2  = (const float*)d_in[8];
  const float* time_w1 = (const float*)d_in[9];
  const float* time_b1 = (const float*)d_in[10];
  const float* time_w2 = (const float*)d_in[11];
  const float* time_b2 = (const float*)d_in[12];
  const float* ar_w1   = (const float*)d_in[13];
  const float* ar_b1   = (const float*)d_in[14];
  const float* ar_w2   = (const float*)d_in[15];
  const float* ar_b2   = (const float*)d_in[16];
  unsigned char* ws8   = (unsigned char*)d_ws;
  float* out           = (float*)d_out;

  prep_kernel<<<dim3((PREP_N + 255) / 256), dim3(256), 0, stream>>>(
      w_ih, w_hh, pit_w1, time_w1, ar_w1, ar_w2, ws8);
  rnn_kernel<<<dim3(16), dim3(NT), 0, stream>>>(
      x, b_ih, b_hh, pit_b1, pit_w2, pit_b2,
      time_w1, time_b1, time_w2, time_b2,
      ar_w1, ar_b1, ar_b2, ws8, out);
}